// Round 3
// baseline (1570.731 us; speedup 1.0000x reference)
//
#include <hip/hip_runtime.h>

#define Gn 128
#define Tn 512
#define Sn 24
#define SP 28   // padded LDS row stride; rows j..j+7 start at 8 distinct bank groups
#define Mn 4
#define COVS_BASE (Gn * Tn * Mn)   // 262144

__device__ __forceinline__ float4 ld4(const float* p) {
    return *reinterpret_cast<const float4*>(p);
}
__device__ __forceinline__ void st4(float* p, float4 v) {
    *reinterpret_cast<float4*>(p) = v;
}
__device__ __forceinline__ float dot4(float4 a, float4 b) {
    return a.x*b.x + a.y*b.y + a.z*b.z + a.w*b.w;
}

struct Row24 { float4 v[6]; };

__device__ __forceinline__ Row24 loadRow(const float* p) {
    Row24 r;
#pragma unroll
    for (int i = 0; i < 6; ++i) r.v[i] = ld4(p + 4*i);
    return r;
}

__device__ __forceinline__ float dot24(const Row24& a, const float* b) {
    float4 b0 = ld4(b+0), b1 = ld4(b+4), b2 = ld4(b+8),
           b3 = ld4(b+12), b4 = ld4(b+16), b5 = ld4(b+20);
    float s0 = a.v[0].x*b0.x + a.v[0].y*b0.y + a.v[0].z*b0.z + a.v[0].w*b0.w;
    float s1 = a.v[1].x*b1.x + a.v[1].y*b1.y + a.v[1].z*b1.z + a.v[1].w*b1.w;
    float s2 = a.v[2].x*b2.x + a.v[2].y*b2.y + a.v[2].z*b2.z + a.v[2].w*b2.w;
    float s3 = a.v[3].x*b3.x + a.v[3].y*b3.y + a.v[3].z*b3.z + a.v[3].w*b3.w;
    float s4 = a.v[4].x*b4.x + a.v[4].y*b4.y + a.v[4].z*b4.z + a.v[4].w*b4.w;
    float s5 = a.v[5].x*b5.x + a.v[5].y*b5.y + a.v[5].z*b5.z + a.v[5].w*b5.w;
    return ((s0+s1)+(s2+s3))+(s4+s5);
}

// Raw barrier: waits only LDS (lgkmcnt), NOT vmcnt -> distance-1 global prefetch
// stays in flight across barriers.
__device__ __forceinline__ void barrierLds() {
    asm volatile("s_waitcnt lgkmcnt(0)" ::: "memory");
    __builtin_amdgcn_s_barrier();
    asm volatile("" ::: "memory");
}
// Wave-internal LDS RAW ordering (single wave, lockstep HW + lgkm wait).
__device__ __forceinline__ void waveLds() {
    asm volatile("s_waitcnt lgkmcnt(0)" ::: "memory");
    __builtin_amdgcn_wave_barrier();
    asm volatile("" ::: "memory");
}

extern "C" __global__ void __launch_bounds__(256)
kalman_kernel(const float* __restrict__ y_g, const float* __restrict__ F_g,
              const float* __restrict__ Q_g, const float* __restrict__ H_g,
              const float* __restrict__ R_g, const float* __restrict__ m0_g,
              const float* __restrict__ P0_g, float* __restrict__ out)
{
    const int g   = blockIdx.x;
    const int tid = threadIdx.x;
    const int gT  = g * Tn;

    __shared__ __align__(16) float sP[Sn*SP];      // covariance (symmetric)
    __shared__ __align__(16) float sG[Sn*SP];      // G = F @ P
    __shared__ __align__(16) float sF[2][Sn*SP];
    __shared__ __align__(16) float sQ[2][Sn*SP];
    __shared__ __align__(16) float sH[2][Mn*SP];
    __shared__ __align__(16) float sR[2][16];
    __shared__ __align__(16) float sy[2][4];
    __shared__ __align__(16) float sHP[Mn*SP];     // H@P rows
    __shared__ __align__(16) float sV[Sn*4];       // V = F @ HP^T, row i = V_i (4)
    __shared__ __align__(16) float sSm[16];
    __shared__ __align__(16) float sInv[16];
    __shared__ __align__(16) float sMean[Sn];
    __shared__ __align__(16) float sFm[Sn];        // F @ m
    __shared__ __align__(16) float sResid[4];
    __shared__ __align__(16) float sr2[4];         // Inv @ resid

    const float4* F4 = reinterpret_cast<const float4*>(F_g);
    const float4* Q4 = reinterpret_cast<const float4*>(Q_g);
    const float4* H4 = reinterpret_cast<const float4*>(H_g);
    const float4* R4 = reinterpret_cast<const float4*>(R_g);
    const float4* y4 = reinterpret_cast<const float4*>(y_g);

    // staging: 317 float4 per step: F 144, Q 144, H 24, R 4, y 1
    auto stage_load = [&](int v, int t) -> float4 {
        if (v < 144)      return F4[(gT + t)*144 + v];
        else if (v < 288) return Q4[(gT + t)*144 + (v-144)];
        else if (v < 312) return H4[(gT + t)*24  + (v-288)];
        else if (v < 316) return R4[(gT + t)*4   + (v-312)];
        else              return y4[gT + t];
    };
    auto stage_store = [&](int v, int bb, float4 val) {
        if (v < 144)      { int r = v/6,        c = (v%6)*4;           st4(&sF[bb][r*SP+c], val); }
        else if (v < 288) { int v2 = v-144; int r = v2/6, c = (v2%6)*4; st4(&sQ[bb][r*SP+c], val); }
        else if (v < 312) { int v2 = v-288; int r = v2/6, c = (v2%6)*4; st4(&sH[bb][r*SP+c], val); }
        else if (v < 316) { st4(&sR[bb][(v-312)*4], val); }
        else              { st4(&sy[bb][0], val); }
    };

    // ---------------- prologue ----------------
    if (tid < 144) {
        int r = tid / 6, c = (tid % 6) * 4;
        st4(&sP[r*SP + c], ld4(&P0_g[g*Sn*Sn + tid*4]));
    } else if (tid < 150) {
        int v = tid - 144;
        st4(&sMean[v*4], ld4(&m0_g[g*Sn + v*4]));
    }
    {   // stage t=0 synchronously
        float4 a0 = stage_load(tid, 0);
        stage_store(tid, 0, a0);
        if (tid < 61) {
            float4 a1 = stage_load(tid + 256, 0);
            stage_store(tid + 256, 0, a1);
        }
    }
    barrierLds();

    float4 pf0, pf1;

    for (int t = 0; t < Tn; ++t) {
        const int  b    = t & 1;
        const int  b1   = b ^ 1;
        const bool last = (t == Tn - 1);

        // ---- Phase A: prefetch-issue(t+1); HP = H@P; mu/resid; most of G = F@P ----
        if (!last) {
            pf0 = stage_load(tid, t+1);
            if (tid < 61) pf1 = stage_load(tid + 256, t+1);
        }
        if (tid < 96) {
            int a = tid / 24, s = tid % 24;            // consecutive rows -> conflict-free
            Row24 hr = loadRow(&sH[b][a*SP]);          // broadcast among 24 lanes
            sHP[a*SP + s] = dot24(hr, &sP[s*SP]);      // P symmetric: col s == row s
        } else if (tid < 100) {
            int a = tid - 96;
            Row24 hr = loadRow(&sH[b][a*SP]);
            float mu = dot24(hr, sMean);
            out[(gT + t)*4 + a] = mu;                  // means output
            sResid[a] = sy[b][a] - mu;
        } else if (!last) {
            // G items 0..467, triple-blocked: 3 consecutive j in one row i
            int o0 = 3*(tid - 100);
            int i = o0/24, j0 = o0%24;
            Row24 fr = loadRow(&sF[b][i*SP]);          // 8-way dedup across wave
#pragma unroll
            for (int d = 0; d < 3; ++d) {
                sG[i*SP + j0 + d] = dot24(fr, &sP[(j0+d)*SP]);
            }
        }
        barrierLds();

        // ---- Phase B: V = F@HP^T; Fm = F@m; rest of G; Sm->Inv->r2 on wave 2 ----
        if (tid < 64) {
            if (!last) {
                if (tid < 32) {                        // V: items a*24+i, triple in i
                    int v0 = 3*tid;
                    int a = v0/24, i0 = v0%24;
                    Row24 hpr = loadRow(&sHP[a*SP]);
#pragma unroll
                    for (int d = 0; d < 3; ++d) {
                        int i = i0 + d;
                        sV[i*4 + a] = dot24(hpr, &sF[b][i*SP]);
                    }
                } else if (tid < 40) {                 // Fm
                    int i0 = 3*(tid - 32);
#pragma unroll
                    for (int d = 0; d < 3; ++d) {
                        int i = i0 + d;
                        Row24 fr = loadRow(&sF[b][i*SP]);
                        sFm[i] = dot24(fr, sMean);
                    }
                } else {                               // G items 468..539
                    int o0 = 468 + 3*(tid - 40);
                    int i = o0/24, j0 = o0%24;
                    Row24 fr = loadRow(&sF[b][i*SP]);
#pragma unroll
                    for (int d = 0; d < 3; ++d) {
                        sG[i*SP + j0 + d] = dot24(fr, &sP[(j0+d)*SP]);
                    }
                }
            }
        } else if (tid < 128) {
            if (!last && tid < 76) {                   // G items 540..575
                int o0 = 540 + 3*(tid - 64);
                int i = o0/24, j0 = o0%24;
                Row24 fr = loadRow(&sF[b][i*SP]);
#pragma unroll
                for (int d = 0; d < 3; ++d) {
                    sG[i*SP + j0 + d] = dot24(fr, &sP[(j0+d)*SP]);
                }
            }
        } else if (tid < 192) {                        // wave 2: Sm -> Inv -> r2
            if (tid < 144) {
                int idx = tid - 128;
                int a = idx >> 2, c = idx & 3;
                Row24 hpr = loadRow(&sHP[a*SP]);
                float sig = dot24(hpr, &sH[b][c*SP]) + sR[b][idx];
                sSm[idx] = sig;
                out[COVS_BASE + (size_t)(gT + t)*16 + idx] = sig;   // covs output
            }
            if (!last) {
                waveLds();
                if (tid < 144) {
                    int idx = tid - 128;
                    float s00=sSm[0],  s01=sSm[1],  s02=sSm[2],  s03=sSm[3];
                    float s10=sSm[4],  s11=sSm[5],  s12=sSm[6],  s13=sSm[7];
                    float s20=sSm[8],  s21=sSm[9],  s22=sSm[10], s23=sSm[11];
                    float s30=sSm[12], s31=sSm[13], s32=sSm[14], s33=sSm[15];
                    float p0 = s00*s11 - s01*s10;
                    float p1 = s00*s12 - s02*s10;
                    float p2 = s00*s13 - s03*s10;
                    float p3 = s01*s12 - s02*s11;
                    float p4 = s01*s13 - s03*s11;
                    float p5 = s02*s13 - s03*s12;
                    float q0c = s20*s31 - s21*s30;
                    float q1c = s20*s32 - s22*s30;
                    float q2c = s20*s33 - s23*s30;
                    float q3c = s21*s32 - s22*s31;
                    float q4c = s21*s33 - s23*s31;
                    float q5c = s22*s33 - s23*s32;
                    float det  = p0*q5c - p1*q4c + p2*q3c + p3*q2c - p4*q1c + p5*q0c;
                    float rdet = 1.0f / det;
                    int ia = idx >> 2, ic = idx & 3;   // Inv[ia][ic] = cof(ic,ia)/det
                    int r0 = (ic==0)?1:0, r1 = (ic<=1)?2:1, r2i = (ic<=2)?3:2;
                    int u0 = (ia==0)?1:0, u1 = (ia<=1)?2:1, u2 = (ia<=2)?3:2;
                    float m00=sSm[r0*4+u0], m01=sSm[r0*4+u1], m02=sSm[r0*4+u2];
                    float m10=sSm[r1*4+u0], m11=sSm[r1*4+u1], m12=sSm[r1*4+u2];
                    float m20=sSm[r2i*4+u0], m21=sSm[r2i*4+u1], m22=sSm[r2i*4+u2];
                    float minor = m00*(m11*m22 - m12*m21)
                                - m01*(m10*m22 - m12*m20)
                                + m02*(m10*m21 - m11*m20);
                    float cof = ((ia + ic) & 1) ? -minor : minor;
                    sInv[idx] = cof * rdet;
                }
                waveLds();
                if (tid < 132) {
                    int a = tid - 128;
                    sr2[a] = dot4(ld4(&sInv[a*4]), ld4(&sResid[0]));
                }
            }
        }
        if (last) return;
        barrierLds();

        // ---- Phase C: P = G@F^T + Q - V Inv V^T ; m = Fm + V r2 ; land prefetch ----
        if (tid < 192) {
            int o0 = 3*tid;
            int i = o0/24, j0 = o0%24;
            Row24 gr = loadRow(&sG[i*SP]);             // 8-way dedup
            float4 vi   = ld4(&sV[i*4]);
            float4 inv0 = ld4(&sInv[0]),  inv1 = ld4(&sInv[4]);
            float4 inv2 = ld4(&sInv[8]),  inv3 = ld4(&sInv[12]);
#pragma unroll
            for (int d = 0; d < 3; ++d) {
                int j = j0 + d;
                float4 vj = ld4(&sV[j*4]);
                float4 tj;
                tj.x = dot4(inv0, vj);
                tj.y = dot4(inv1, vj);
                tj.z = dot4(inv2, vj);
                tj.w = dot4(inv3, vj);
                float val = dot24(gr, &sF[b][j*SP]) + sQ[b][i*SP + j] - dot4(vi, tj);
                sP[i*SP + j] = val;
            }
        } else if (tid < 216) {
            int s = tid - 192;
            sMean[s] = sFm[s] + dot4(ld4(&sV[s*4]), ld4(&sr2[0]));
        }
        // land the t+1 prefetch into the other staging buffer
        stage_store(tid, b1, pf0);
        if (tid < 61) stage_store(tid + 256, b1, pf1);
        barrierLds();
    }
}

extern "C" void kernel_launch(void* const* d_in, const int* in_sizes, int n_in,
                              void* d_out, int out_size, void* d_ws, size_t ws_size,
                              hipStream_t stream) {
    kalman_kernel<<<Gn, 256, 0, stream>>>(
        (const float*)d_in[0], (const float*)d_in[1], (const float*)d_in[2],
        (const float*)d_in[3], (const float*)d_in[4], (const float*)d_in[5],
        (const float*)d_in[6], (float*)d_out);
}

// Round 4
// 1291.874 us; speedup vs baseline: 1.2159x; 1.2159x over previous
//
#include <hip/hip_runtime.h>

#define Gn 128
#define Tn 512
#define Sn 24
#define SP 28   // padded LDS row stride (16B aligned)
#define Mn 4
#define COVS_BASE (Gn * Tn * Mn)   // 262144

__device__ __forceinline__ float4 ld4(const float* p) {
    return *reinterpret_cast<const float4*>(p);
}
__device__ __forceinline__ void st4(float* p, float4 v) {
    *reinterpret_cast<float4*>(p) = v;
}
__device__ __forceinline__ float dot4(float4 a, float4 b) {
    return a.x*b.x + a.y*b.y + a.z*b.z + a.w*b.w;
}

struct Row24 { float4 v[6]; };

__device__ __forceinline__ Row24 loadRow(const float* p) {
    Row24 r;
#pragma unroll
    for (int i = 0; i < 6; ++i) r.v[i] = ld4(p + 4*i);
    return r;
}

__device__ __forceinline__ float dot24(const Row24& a, const float* b) {
    float4 b0 = ld4(b+0), b1 = ld4(b+4), b2 = ld4(b+8),
           b3 = ld4(b+12), b4 = ld4(b+16), b5 = ld4(b+20);
    float s0 = a.v[0].x*b0.x + a.v[0].y*b0.y + a.v[0].z*b0.z + a.v[0].w*b0.w;
    float s1 = a.v[1].x*b1.x + a.v[1].y*b1.y + a.v[1].z*b1.z + a.v[1].w*b1.w;
    float s2 = a.v[2].x*b2.x + a.v[2].y*b2.y + a.v[2].z*b2.z + a.v[2].w*b2.w;
    float s3 = a.v[3].x*b3.x + a.v[3].y*b3.y + a.v[3].z*b3.z + a.v[3].w*b3.w;
    float s4 = a.v[4].x*b4.x + a.v[4].y*b4.y + a.v[4].z*b4.z + a.v[4].w*b4.w;
    float s5 = a.v[5].x*b5.x + a.v[5].y*b5.y + a.v[5].z*b5.z + a.v[5].w*b5.w;
    return ((s0+s1)+(s2+s3))+(s4+s5);
}

// Raw barrier: waits only LDS (lgkmcnt), NOT vmcnt -> distance-1 global prefetch
// stays in flight across barriers.
__device__ __forceinline__ void barrierLds() {
    asm volatile("s_waitcnt lgkmcnt(0)" ::: "memory");
    __builtin_amdgcn_s_barrier();
    asm volatile("" ::: "memory");
}
// Wave-internal LDS RAW ordering (single wave, lockstep HW + lgkm wait).
__device__ __forceinline__ void waveLds() {
    asm volatile("s_waitcnt lgkmcnt(0)" ::: "memory");
    __builtin_amdgcn_wave_barrier();
    asm volatile("" ::: "memory");
}

extern "C" __global__ void __launch_bounds__(256)
kalman_kernel(const float* __restrict__ y_g, const float* __restrict__ F_g,
              const float* __restrict__ Q_g, const float* __restrict__ H_g,
              const float* __restrict__ R_g, const float* __restrict__ m0_g,
              const float* __restrict__ P0_g, float* __restrict__ out)
{
    const int g    = blockIdx.x;
    const int tid  = threadIdx.x;
    const int gT   = g * Tn;
    const int lane = tid & 63;
    const int w    = tid >> 6;      // wave 0..3
    const int h    = lane >> 5;     // half-wave 0/1
    const int r    = lane & 31;     // row slot 0..31

    __shared__ __align__(16) float sP[Sn*SP];      // covariance (symmetric)
    __shared__ __align__(16) float sG[Sn*SP];      // G = F @ P
    __shared__ __align__(16) float sF[2][Sn*SP];
    __shared__ __align__(16) float sQ[2][Sn*SP];
    __shared__ __align__(16) float sH[2][Mn*SP];
    __shared__ __align__(16) float sR[2][16];
    __shared__ __align__(16) float sy[2][4];
    __shared__ __align__(16) float sHP[Mn*SP];     // H@P rows
    __shared__ __align__(16) float sV[Sn*4];       // V = F @ HP^T
    __shared__ __align__(16) float sSm[16];
    __shared__ __align__(16) float sInv[16];
    __shared__ __align__(16) float sMean[Sn];
    __shared__ __align__(16) float sFm[Sn];        // F @ m
    __shared__ __align__(16) float sResid[4];
    __shared__ __align__(16) float sr2[4];         // Inv @ resid

    const float4* F4 = reinterpret_cast<const float4*>(F_g);
    const float4* Q4 = reinterpret_cast<const float4*>(Q_g);
    const float4* H4 = reinterpret_cast<const float4*>(H_g);
    const float4* R4 = reinterpret_cast<const float4*>(R_g);
    const float4* y4 = reinterpret_cast<const float4*>(y_g);

    // staging: 317 float4 per step: F 144, Q 144, H 24, R 4, y 1
    auto stage_load = [&](int v, int t) -> float4 {
        if (v < 144)      return F4[(gT + t)*144 + v];
        else if (v < 288) return Q4[(gT + t)*144 + (v-144)];
        else if (v < 312) return H4[(gT + t)*24  + (v-288)];
        else if (v < 316) return R4[(gT + t)*4   + (v-312)];
        else              return y4[gT + t];
    };
    auto stage_store = [&](int v, int bb, float4 val) {
        if (v < 144)      { int rr = v/6,        c = (v%6)*4;            st4(&sF[bb][rr*SP+c], val); }
        else if (v < 288) { int v2 = v-144; int rr = v2/6, c = (v2%6)*4; st4(&sQ[bb][rr*SP+c], val); }
        else if (v < 312) { int v2 = v-288; int rr = v2/6, c = (v2%6)*4; st4(&sH[bb][rr*SP+c], val); }
        else if (v < 316) { st4(&sR[bb][(v-312)*4], val); }
        else              { st4(&sy[bb][0], val); }
    };

    // ---------------- prologue ----------------
    if (tid < 144) {
        int rr = tid / 6, c = (tid % 6) * 4;
        st4(&sP[rr*SP + c], ld4(&P0_g[g*Sn*Sn + tid*4]));
    } else if (tid < 150) {
        int v = tid - 144;
        st4(&sMean[v*4], ld4(&m0_g[g*Sn + v*4]));
    }
    {   // stage t=0 synchronously
        float4 a0 = stage_load(tid, 0);
        stage_store(tid, 0, a0);
        if (tid < 61) {
            float4 a1 = stage_load(tid + 256, 0);
            stage_store(tid + 256, 0, a1);
        }
    }
    barrierLds();

    float4 pf0, pf1;
    float  part[4];

    for (int t = 0; t < Tn; ++t) {
        const int  b    = t & 1;
        const int  b1   = b ^ 1;
        const bool last = (t == Tn - 1);

        // ==== Phase A: prefetch-issue(t+1); uniform dot loop:
        //   lanes r<24   : G[r][j] = dot(F[r], P[j])      (P[j] wave-broadcast)
        //   lanes 24..27 : HP[r-24][j] = dot(H[r-24], P[j]) (same broadcast!)
        //   lanes 28..31 : mu[r-28] = dot(H[r-28], mean)  (d==0, w==0, h==0 only)
        if (!last) {
            pf0 = stage_load(tid, t+1);
            if (tid < 61) pf1 = stage_load(tid + 256, t+1);
        }
        {
            const float* statp = (r < 24) ? &sF[b][r*SP]
                                          : &sH[b][((r-24)&3)*SP];
            Row24 stat = loadRow(statp);
#pragma unroll
            for (int d = 0; d < 3; ++d) {
                int j = 6*w + 3*h + d;
                const float* bp = (r < 28) ? &sP[j*SP] : &sMean[0];
                float val = dot24(stat, bp);
                if (r < 24) {
                    sG[r*SP + j] = val;
                } else if (r < 28) {
                    sHP[(r-24)*SP + j] = val;
                } else if (d == 0 && h == 0 && w == 0) {
                    int a = r - 28;
                    out[(gT + t)*4 + a] = val;        // means output
                    sResid[a] = sy[b][a] - val;
                }
            }
        }
        barrierLds();

        // ==== Phase B:
        //   wave 3      : Sm -> Sig out -> Inv -> r2 (serial chain, alone)
        //   waves 0..2  : r<24: 4 reg-partials of G@F^T (F[j] broadcast)
        //                 r>=24 (free lanes): V = F@HP^T and Fm = F@m
        if (w == 3) {
            if (lane < 16) {
                int a = lane >> 2, c = lane & 3;
                Row24 hpr = loadRow(&sHP[a*SP]);
                float sig = dot24(hpr, &sH[b][c*SP]) + sR[b][lane];
                sSm[lane] = sig;
                out[COVS_BASE + (size_t)(gT + t)*16 + lane] = sig;  // covs output
            }
            if (!last) {
                waveLds();
                if (lane < 16) {
                    float s00=sSm[0],  s01=sSm[1],  s02=sSm[2],  s03=sSm[3];
                    float s10=sSm[4],  s11=sSm[5],  s12=sSm[6],  s13=sSm[7];
                    float s20=sSm[8],  s21=sSm[9],  s22=sSm[10], s23=sSm[11];
                    float s30=sSm[12], s31=sSm[13], s32=sSm[14], s33=sSm[15];
                    float p0 = s00*s11 - s01*s10;
                    float p1 = s00*s12 - s02*s10;
                    float p2 = s00*s13 - s03*s10;
                    float p3 = s01*s12 - s02*s11;
                    float p4 = s01*s13 - s03*s11;
                    float p5 = s02*s13 - s03*s12;
                    float q0c = s20*s31 - s21*s30;
                    float q1c = s20*s32 - s22*s30;
                    float q2c = s20*s33 - s23*s30;
                    float q3c = s21*s32 - s22*s31;
                    float q4c = s21*s33 - s23*s31;
                    float q5c = s22*s33 - s23*s32;
                    float det  = p0*q5c - p1*q4c + p2*q3c + p3*q2c - p4*q1c + p5*q0c;
                    float rdet = 1.0f / det;
                    int ia = lane >> 2, ic = lane & 3;   // Inv[ia][ic] = cof(ic,ia)/det
                    int r0 = (ic==0)?1:0, r1 = (ic<=1)?2:1, r2i = (ic<=2)?3:2;
                    int u0 = (ia==0)?1:0, u1 = (ia<=1)?2:1, u2 = (ia<=2)?3:2;
                    float m00=sSm[r0*4+u0],  m01=sSm[r0*4+u1],  m02=sSm[r0*4+u2];
                    float m10=sSm[r1*4+u0],  m11=sSm[r1*4+u1],  m12=sSm[r1*4+u2];
                    float m20=sSm[r2i*4+u0], m21=sSm[r2i*4+u1], m22=sSm[r2i*4+u2];
                    float minor = m00*(m11*m22 - m12*m21)
                                - m01*(m10*m22 - m12*m20)
                                + m02*(m10*m21 - m11*m20);
                    float cof = ((ia + ic) & 1) ? -minor : minor;
                    sInv[lane] = cof * rdet;
                }
                waveLds();
                if (lane < 4) {
                    sr2[lane] = dot4(ld4(&sInv[lane*4]), ld4(&sResid[0]));
                }
            }
        } else if (!last) {
            if (r < 24) {
                Row24 gr = loadRow(&sG[r*SP]);
#pragma unroll
                for (int d = 0; d < 4; ++d) {
                    int j = 8*w + 4*h + d;
                    part[d] = dot24(gr, &sF[b][j*SP]);   // F[j] broadcast
                }
            } else {
                int q = w*16 + h*8 + (r - 24);           // 0..47 free-lane id
                if (q < 32) {                            // V: a = q>>3, i = (q&7)*3+d
                    int a = q >> 3, i0 = (q & 7) * 3;
                    Row24 hpr = loadRow(&sHP[a*SP]);
#pragma unroll
                    for (int d = 0; d < 3; ++d)
                        sV[(i0+d)*4 + a] = dot24(hpr, &sF[b][(i0+d)*SP]);
                } else if (q < 40) {                     // Fm = F @ m (mean stationary)
                    int i0 = (q - 32) * 3;
                    Row24 mr = loadRow(&sMean[0]);
#pragma unroll
                    for (int d = 0; d < 3; ++d)
                        sFm[i0+d] = dot24(mr, &sF[b][(i0+d)*SP]);
                }
            }
        }
        if (last) return;
        barrierLds();

        // ==== Phase C: P = partials + Q - V Inv V^T ; mean = Fm + V r2 ; land prefetch
        if (w < 3) {
            if (r < 24) {
                float4 vr  = ld4(&sV[r*4]);
                float4 i0v = ld4(&sInv[0]),  i1v = ld4(&sInv[4]);
                float4 i2v = ld4(&sInv[8]),  i3v = ld4(&sInv[12]);
                float4 ur;
                ur.x = dot4(i0v, vr); ur.y = dot4(i1v, vr);
                ur.z = dot4(i2v, vr); ur.w = dot4(i3v, vr);
#pragma unroll
                for (int d = 0; d < 4; ++d) {
                    int j = 8*w + 4*h + d;
                    float4 vj = ld4(&sV[j*4]);
                    sP[r*SP + j] = part[d] + sQ[b][r*SP + j] - dot4(ur, vj);
                }
            }
        } else {
            if (lane < 24) {
                sMean[lane] = sFm[lane] + dot4(ld4(&sV[lane*4]), ld4(&sr2[0]));
            }
        }
        // land the t+1 prefetch into the other staging buffer
        stage_store(tid, b1, pf0);
        if (tid < 61) stage_store(tid + 256, b1, pf1);
        barrierLds();
    }
}

extern "C" void kernel_launch(void* const* d_in, const int* in_sizes, int n_in,
                              void* d_out, int out_size, void* d_ws, size_t ws_size,
                              hipStream_t stream) {
    kalman_kernel<<<Gn, 256, 0, stream>>>(
        (const float*)d_in[0], (const float*)d_in[1], (const float*)d_in[2],
        (const float*)d_in[3], (const float*)d_in[4], (const float*)d_in[5],
        (const float*)d_in[6], (float*)d_out);
}